// Round 3
// baseline (401.567 us; speedup 1.0000x reference)
//
#include <hip/hip_runtime.h>
#include <hip/hip_fp16.h>
#include <cstddef>

// AffinityPropagate: per-pixel normalized 3x3 stencil, 24 steps.
// R3: tile 80x60 -> grid 8x8x8 = 512 blocks = exactly 2 blocks/CU x 256 CUs
// (kills R2's 1.5x round quantization at 640 blocks). Weights normalized ONCE
// by a precompute kernel into d_ws as packed half8 (16B/px, one dwordx4) +
// f32 center plane; 3 fused dispatches of T=8 steps each ping-pong frames in
// LDS. Per-thread 4x4 pixel units with 16B-aligned LDS reads.
//
// Tap order: w0=NW w1=N w2=NE w3=W [center] w4=E w5=SW w6=S w7=SE
//
// Ring/frontier: staged input halo 9 (98x78), weight region halo 8 (96x76).
// After step s the correct region is rings <= 9-s; after 8 steps rings <= 1
// superset of the 80x60 output. Stale outer rings (buffer B zero-filled,
// A keeps stage-time data) only contaminate rings >= 2 by step 8 — harmless.
// Out-of-image pixels get all-zero weights -> stay exactly 0 = zero padding.

#define HIMG 480
#define WIMG 640
#define HW   (HIMG * WIMG)
#define BN   8

#define TW     80
#define TH     60
#define TSTEPS 8
#define IH     9                 // input halo
#define WHL    8                 // weight halo
#define SWD    (TW + 2 * IH)     // 98 staged cols
#define SHT    (TH + 2 * IH)     // 78 staged rows
#define PITCH  100               // LDS row pitch (mult of 4 for b128 alignment)
#define NT     512
#define UXN    ((TW + 2 * WHL) / 4)   // 24 x-units
#define UYN    ((TH + 2 * WHL) / 4)   // 19 y-units
#define NUNITS (UXN * UYN)            // 456

#define WS_FRAME_B  ((size_t)BN * HW * 4)            // 9,830,400
#define WS_WA_B     ((size_t)BN * HW * 16)           // 39,321,600
#define WS_WC_B     ((size_t)BN * HW * 4)            // 9,830,400
#define WS_NEED     (WS_FRAME_B + WS_WA_B + WS_WC_B) // 58,982,400

// ---------------- precompute: normalize affinity -> packed half8 + f32 center
__global__ __launch_bounds__(256) void precompute_w(
    const float* __restrict__ aff,
    __half2* __restrict__ wA,
    float* __restrict__ wC)
{
    int i = blockIdx.x * 256 + threadIdx.x;      // [0, BN*HW), exact multiple
    int b = i / HW;
    int p = i - b * HW;
    const float* a = aff + (size_t)b * 8 * HW + p;

    float w[8];
    float s = 0.f;
    #pragma unroll
    for (int c = 0; c < 8; ++c) { w[c] = a[(size_t)c * HW]; s += fabsf(w[c]); }
    float r = 1.0f / s;
    float acc = 0.f;
    #pragma unroll
    for (int c = 0; c < 8; ++c) { w[c] *= r; acc += w[c]; }
    float ctr = 1.0f - acc;

    union { float4 f4; __half2 h[4]; } u;
    u.h[0] = __floats2half2_rn(w[0], w[1]);
    u.h[1] = __floats2half2_rn(w[2], w[3]);
    u.h[2] = __floats2half2_rn(w[4], w[5]);
    u.h[3] = __floats2half2_rn(w[6], w[7]);
    *(float4*)(wA + 4 * (size_t)i) = u.f4;
    wC[i] = ctr;
}

// ---------------- fused T=8 stencil kernel
#define TAPS(py, j, ra, rb, rc)                                   \
  ( wc[py][j] * rb[(j) + 1]                                       \
  + __low2float (wv[py][j][0]) * ra[(j)    ]                      \
  + __high2float(wv[py][j][0]) * ra[(j) + 1]                      \
  + __low2float (wv[py][j][1]) * ra[(j) + 2]                      \
  + __high2float(wv[py][j][1]) * rb[(j)    ]                      \
  + __low2float (wv[py][j][2]) * rb[(j) + 2]                      \
  + __high2float(wv[py][j][2]) * rc[(j)    ]                      \
  + __low2float (wv[py][j][3]) * rc[(j) + 1]                      \
  + __high2float(wv[py][j][3]) * rc[(j) + 2] )

#define LOAD6(r, p) do {                                          \
    float4 q_ = *(const float4*)(p);                              \
    float2 t_ = *(const float2*)((p) + 4);                        \
    r[0] = q_.x; r[1] = q_.y; r[2] = q_.z; r[3] = q_.w;           \
    r[4] = t_.x; r[5] = t_.y; } while (0)

#define STROW(py, ra, rb, rc) do {                                \
    float a0_ = TAPS(py, 0, ra, rb, rc);                          \
    float a1_ = TAPS(py, 1, ra, rb, rc);                          \
    float a2_ = TAPS(py, 2, ra, rb, rc);                          \
    float a3_ = TAPS(py, 3, ra, rb, rc);                          \
    float* wp_ = wrow + (py) * PITCH;                             \
    wp_[0] = a0_;                                                 \
    *(float2*)(wp_ + 1) = make_float2(a1_, a2_);                  \
    wp_[3] = a3_; } while (0)

template <bool PRE>
__global__ __launch_bounds__(NT, 4) void affprop8(
    const float* __restrict__ aff,
    const __half2* __restrict__ wA,
    const float* __restrict__ wC,
    const float* __restrict__ src,
    float* __restrict__ dst)
{
    __shared__ __align__(16) float fA[SHT * PITCH];
    __shared__ __align__(16) float fB[SHT * PITCH];

    const int tid = threadIdx.x;
    const int ox  = blockIdx.x * TW;
    const int oy  = blockIdx.y * TH;
    const int b   = blockIdx.z;

    const float* __restrict__ sb = src + (size_t)b * HW;
    float*       __restrict__ db = dst + (size_t)b * HW;

    // ---- stage input region (scalar loads, zero outside image)
    for (int i = tid; i < SHT * SWD; i += NT) {
        int r  = i / SWD;
        int c  = i - r * SWD;
        int gy = oy - IH + r;
        int gx = ox - IH + c;
        float v = 0.f;
        if ((unsigned)gy < (unsigned)HIMG && (unsigned)gx < (unsigned)WIMG)
            v = sb[gy * WIMG + gx];
        fA[r * PITCH + c] = v;
    }
    // ---- zero-fill buffer B (deterministic stale rings)
    for (int i = tid; i < SHT * PITCH / 4; i += NT)
        *(float4*)&fB[4 * i] = make_float4(0.f, 0.f, 0.f, 0.f);

    // ---- per-unit weights (4x4 pixels), resident in VGPRs for all 8 steps
    const bool act = tid < NUNITS;
    const int  ux  = tid % UXN;
    const int  uy  = tid / UXN;

    __half2 wv[4][4][4];
    float   wc[4][4];

    if (act) {
        #pragma unroll
        for (int py = 0; py < 4; ++py) {
            int gy = oy - WHL + 4 * uy + py;
            #pragma unroll
            for (int j = 0; j < 4; ++j) {
                int gx = ox - WHL + 4 * ux + j;
                bool in = (unsigned)gy < (unsigned)HIMG && (unsigned)gx < (unsigned)WIMG;
                if (PRE) {
                    if (in) {
                        size_t idx = (size_t)b * HW + (size_t)gy * WIMG + gx;
                        union { float4 f4; __half2 h[4]; } u;
                        u.f4 = *(const float4*)(wA + 4 * idx);
                        wv[py][j][0] = u.h[0]; wv[py][j][1] = u.h[1];
                        wv[py][j][2] = u.h[2]; wv[py][j][3] = u.h[3];
                        wc[py][j] = wC[idx];
                    } else {
                        __half2 z = __floats2half2_rn(0.f, 0.f);
                        wv[py][j][0] = z; wv[py][j][1] = z;
                        wv[py][j][2] = z; wv[py][j][3] = z;
                        wc[py][j] = 0.f;
                    }
                } else {
                    float w[8];
                    float s = 0.f;
                    if (in) {
                        const float* ap = aff + (size_t)b * 8 * HW + (size_t)gy * WIMG + gx;
                        #pragma unroll
                        for (int c = 0; c < 8; ++c) { w[c] = ap[(size_t)c * HW]; s += fabsf(w[c]); }
                    } else {
                        #pragma unroll
                        for (int c = 0; c < 8; ++c) w[c] = 0.f;
                        s = 1.f;
                    }
                    float rr  = in ? 1.0f / s : 0.f;
                    float acc = 0.f;
                    #pragma unroll
                    for (int c = 0; c < 8; ++c) { w[c] *= rr; acc += w[c]; }
                    wv[py][j][0] = __floats2half2_rn(w[0], w[1]);
                    wv[py][j][1] = __floats2half2_rn(w[2], w[3]);
                    wv[py][j][2] = __floats2half2_rn(w[4], w[5]);
                    wv[py][j][3] = __floats2half2_rn(w[6], w[7]);
                    wc[py][j] = in ? 1.0f - acc : 0.f;
                }
            }
        }
    }
    __syncthreads();

    // ---- 8 fused steps, LDS ping-pong, rolling 3-row register window
    const float* fin = fA;
    float*       fo  = fB;
    const int rbase = 4 * uy;       // staged top row of 6-row read window
    const int cbase = 4 * ux;       // staged left col (16B-aligned)

    #pragma unroll 1
    for (int s = 0; s < TSTEPS; ++s) {
        if (act) {
            const float* rp = fin + rbase * PITCH + cbase;
            float* wrow = fo + (rbase + 1) * PITCH + cbase + 1;
            float r0[6], r1[6], r2[6];
            LOAD6(r0, rp);
            LOAD6(r1, rp + PITCH);
            LOAD6(r2, rp + 2 * PITCH);
            STROW(0, r0, r1, r2);
            LOAD6(r0, rp + 3 * PITCH);
            STROW(1, r1, r2, r0);
            LOAD6(r1, rp + 4 * PITCH);
            STROW(2, r2, r0, r1);
            LOAD6(r2, rp + 5 * PITCH);
            STROW(3, r0, r1, r2);
        }
        __syncthreads();
        const float* t = fin; fin = fo; fo = (float*)t;
    }

    // ---- store 80x60 tile (fin == fA after 8 steps)
    for (int i = tid; i < TH * (TW / 4); i += NT) {
        int r  = i / (TW / 4);
        int c4 = (i - r * (TW / 4)) * 4;
        const float* p = fin + (IH + r) * PITCH + IH + c4;
        float4 v = make_float4(p[0], p[1], p[2], p[3]);
        *(float4*)&db[(size_t)(oy + r) * WIMG + ox + c4] = v;
    }
}

extern "C" void kernel_launch(void* const* d_in, const int* in_sizes, int n_in,
                              void* d_out, int out_size, void* d_ws, size_t ws_size,
                              hipStream_t stream)
{
    const float* aff  = (const float*)d_in[0];
    const float* feat = (const float*)d_in[1];
    float* out = (float*)d_out;

    char* ws = (char*)d_ws;
    float*   wsFrame = (float*)ws;
    __half2* wA      = (__half2*)(ws + WS_FRAME_B);
    float*   wC      = (float*)(ws + WS_FRAME_B + WS_WA_B);

    dim3 blk(NT, 1, 1);
    dim3 grd(WIMG / TW, HIMG / TH, BN);   // 8 x 8 x 8 = 512 blocks

    if (ws_size >= WS_NEED) {
        precompute_w<<<dim3(BN * HW / 256), dim3(256), 0, stream>>>(aff, wA, wC);
        affprop8<true><<<grd, blk, 0, stream>>>(aff, wA, wC, feat, out);
        affprop8<true><<<grd, blk, 0, stream>>>(aff, wA, wC, out, wsFrame);
        affprop8<true><<<grd, blk, 0, stream>>>(aff, wA, wC, wsFrame, out);
    } else {
        // fallback: normalize in-kernel (needs only one frame of scratch)
        affprop8<false><<<grd, blk, 0, stream>>>(aff, nullptr, nullptr, feat, out);
        affprop8<false><<<grd, blk, 0, stream>>>(aff, nullptr, nullptr, out, wsFrame);
        affprop8<false><<<grd, blk, 0, stream>>>(aff, nullptr, nullptr, wsFrame, out);
    }
}

// Round 4
// 264.343 us; speedup vs baseline: 1.5191x; 1.5191x over previous
//
#include <hip/hip_runtime.h>
#include <hip/hip_fp16.h>
#include <cstddef>

// AffinityPropagate: per-pixel normalized 3x3 stencil, 24 steps.
// R4: T=12 steps/launch x 2 launches. Tile 40x40 -> weight region 64x64 =
// exactly 512 units of 2x4 px (every thread active, no mask). Per-thread
// weight footprint 40 VGPRs (R3's 80 spilled to scratch: WRITE_SIZE 67MB vs
// 9.8MB output). Grid 16x12x8=1536 = 3 exact rounds at 2 blocks/CU.
// Weights precomputed once into d_ws as packed half8 taps + f32 center.
//
// Tap order: w0=NW w1=N w2=NE w3=W [center] w4=E w5=SW w6=S w7=SE
//
// Ring/frontier: staged input halo 13 (66x66), weight halo 12 (64x64).
// After step s rings <= 12-s are correct; after 12 steps the 40x40 output
// tile is exact. Out-of-image px get all-zero weights -> stay exactly 0.

#define HIMG 480
#define WIMG 640
#define HW   (HIMG * WIMG)
#define BN   8

#define TILE   40
#define TSTEPS 12
#define IH     13                // input halo (staged)
#define WHL    12                // weight halo
#define SW     (TILE + 2 * IH)   // 66 staged rows/cols
#define PITCH  68                // LDS row pitch (mult of 4 -> b128 align)
#define NT     512
#define UXN    16                // x-units (4 px wide)
#define UYN    32                // y-units (2 px tall)  -> 512 units exactly

#define WS_FRAME_B  ((size_t)BN * HW * 4)            // 9,830,400
#define WS_WA_B     ((size_t)BN * HW * 16)           // 39,321,600
#define WS_WC_B     ((size_t)BN * HW * 4)            // 9,830,400
#define WS_NEED     (WS_FRAME_B + WS_WA_B + WS_WC_B) // 58,982,400

// ---------------- precompute: normalize affinity -> packed half8 + f32 center
__global__ __launch_bounds__(256) void precompute_w(
    const float* __restrict__ aff,
    __half2* __restrict__ wA,
    float* __restrict__ wC)
{
    int i = blockIdx.x * 256 + threadIdx.x;      // [0, BN*HW)
    int b = i / HW;
    int p = i - b * HW;
    const float* a = aff + (size_t)b * 8 * HW + p;

    float w[8];
    float s = 0.f;
    #pragma unroll
    for (int c = 0; c < 8; ++c) { w[c] = a[(size_t)c * HW]; s += fabsf(w[c]); }
    float r = 1.0f / s;
    float acc = 0.f;
    #pragma unroll
    for (int c = 0; c < 8; ++c) { w[c] *= r; acc += w[c]; }
    float ctr = 1.0f - acc;

    union { float4 f4; __half2 h[4]; } u;
    u.h[0] = __floats2half2_rn(w[0], w[1]);
    u.h[1] = __floats2half2_rn(w[2], w[3]);
    u.h[2] = __floats2half2_rn(w[4], w[5]);
    u.h[3] = __floats2half2_rn(w[6], w[7]);
    *(float4*)(wA + 4 * (size_t)i) = u.f4;
    wC[i] = ctr;
}

// one output pixel: 9 taps (ra/rb/rc = window rows above/at/below)
#define TAPS(P, ra, rb, rc, J)                                    \
  ( wcc[P] * rb[(J) + 1]                                          \
  + __low2float (wv[P][0]) * ra[(J)    ]                          \
  + __high2float(wv[P][0]) * ra[(J) + 1]                          \
  + __low2float (wv[P][1]) * ra[(J) + 2]                          \
  + __high2float(wv[P][1]) * rb[(J)    ]                          \
  + __low2float (wv[P][2]) * rb[(J) + 2]                          \
  + __high2float(wv[P][2]) * rc[(J)    ]                          \
  + __low2float (wv[P][3]) * rc[(J) + 1]                          \
  + __high2float(wv[P][3]) * rc[(J) + 2] )

#define LOAD6(r, p) do {                                          \
    float4 q_ = *(const float4*)(p);                              \
    float2 t_ = *(const float2*)((p) + 4);                        \
    r[0] = q_.x; r[1] = q_.y; r[2] = q_.z; r[3] = q_.w;           \
    r[4] = t_.x; r[5] = t_.y; } while (0)

template <bool PRE>
__global__ __launch_bounds__(NT, 4) void affprop12(
    const float* __restrict__ aff,
    const __half2* __restrict__ wA,
    const float* __restrict__ wC,
    const float* __restrict__ src,
    float* __restrict__ dst)
{
    __shared__ __align__(16) float fA[SW * PITCH];
    __shared__ __align__(16) float fB[SW * PITCH];

    const int tid = threadIdx.x;
    const int ox  = blockIdx.x * TILE;
    const int oy  = blockIdx.y * TILE;
    const int b   = blockIdx.z;

    const float* __restrict__ sb = src + (size_t)b * HW;
    float*       __restrict__ db = dst + (size_t)b * HW;

    // ---- stage input region [oy-13, oy+53) x [ox-13, ox+53), 0 outside image
    for (int i = tid; i < SW * SW; i += NT) {
        int r  = i / SW;
        int c  = i - r * SW;
        int gy = oy - IH + r;
        int gx = ox - IH + c;
        float v = 0.f;
        if ((unsigned)gy < (unsigned)HIMG && (unsigned)gx < (unsigned)WIMG)
            v = sb[gy * WIMG + gx];
        fA[r * PITCH + c] = v;
    }
    // ---- zero-fill buffer B (deterministic stale rings)
    for (int i = tid; i < SW * PITCH / 4; i += NT)
        *(float4*)&fB[4 * i] = make_float4(0.f, 0.f, 0.f, 0.f);

    // ---- per-unit (2x4 px) weights, resident in VGPRs for all 12 steps
    const int ux = tid & (UXN - 1);     // 0..15
    const int uy = tid >> 4;            // 0..31

    __half2 wv[8][4];   // [px p=py*4+j][tap pair (01)(23)(45)(67)]
    float   wcc[8];     // center weights (f32)

    #pragma unroll
    for (int p = 0; p < 8; ++p) {
        int py = p >> 2, j = p & 3;
        int gy = oy - WHL + 2 * uy + py;
        int gx = ox - WHL + 4 * ux + j;
        bool in = (unsigned)gy < (unsigned)HIMG && (unsigned)gx < (unsigned)WIMG;
        if (PRE) {
            if (in) {
                size_t idx = (size_t)b * HW + (size_t)gy * WIMG + gx;
                union { float4 f4; __half2 h[4]; } u;
                u.f4 = *(const float4*)(wA + 4 * idx);
                wv[p][0] = u.h[0]; wv[p][1] = u.h[1];
                wv[p][2] = u.h[2]; wv[p][3] = u.h[3];
                wcc[p] = wC[idx];
            } else {
                __half2 z = __floats2half2_rn(0.f, 0.f);
                wv[p][0] = z; wv[p][1] = z; wv[p][2] = z; wv[p][3] = z;
                wcc[p] = 0.f;
            }
        } else {
            float w[8];
            float s = 0.f;
            if (in) {
                const float* ap = aff + (size_t)b * 8 * HW + (size_t)gy * WIMG + gx;
                #pragma unroll
                for (int c = 0; c < 8; ++c) { w[c] = ap[(size_t)c * HW]; s += fabsf(w[c]); }
            } else {
                #pragma unroll
                for (int c = 0; c < 8; ++c) w[c] = 0.f;
                s = 1.f;
            }
            float rr  = in ? 1.0f / s : 0.f;
            float acc = 0.f;
            #pragma unroll
            for (int c = 0; c < 8; ++c) { w[c] *= rr; acc += w[c]; }
            wv[p][0] = __floats2half2_rn(w[0], w[1]);
            wv[p][1] = __floats2half2_rn(w[2], w[3]);
            wv[p][2] = __floats2half2_rn(w[4], w[5]);
            wv[p][3] = __floats2half2_rn(w[6], w[7]);
            wcc[p] = in ? 1.0f - acc : 0.f;
        }
    }
    __syncthreads();

    // ---- 12 fused steps, LDS ping-pong
    const float* fin = fA;
    float*       fo  = fB;
    const int rbase = 2 * uy;           // staged top row of 4-row window
    const int cbase = 4 * ux;           // staged left col (16B-aligned)

    #pragma unroll 1
    for (int s = 0; s < TSTEPS; ++s) {
        const float* rp = fin + rbase * PITCH + cbase;
        float r0[6], r1[6], r2[6], r3[6];
        LOAD6(r0, rp);
        LOAD6(r1, rp + PITCH);
        LOAD6(r2, rp + 2 * PITCH);
        LOAD6(r3, rp + 3 * PITCH);

        float* wp0 = fo + (rbase + 1) * PITCH + cbase + 1;
        {   // out row py=0 (window rows r0,r1,r2)
            float a0 = TAPS(0, r0, r1, r2, 0);
            float a1 = TAPS(1, r0, r1, r2, 1);
            float a2 = TAPS(2, r0, r1, r2, 2);
            float a3 = TAPS(3, r0, r1, r2, 3);
            wp0[0] = a0;
            *(float2*)(wp0 + 1) = make_float2(a1, a2);
            wp0[3] = a3;
        }
        {   // out row py=1 (window rows r1,r2,r3)
            float a0 = TAPS(4, r1, r2, r3, 0);
            float a1 = TAPS(5, r1, r2, r3, 1);
            float a2 = TAPS(6, r1, r2, r3, 2);
            float a3 = TAPS(7, r1, r2, r3, 3);
            float* wp1 = wp0 + PITCH;
            wp1[0] = a0;
            *(float2*)(wp1 + 1) = make_float2(a1, a2);
            wp1[3] = a3;
        }
        __syncthreads();
        const float* t = fin; fin = fo; fo = (float*)t;
    }

    // ---- store 40x40 tile (fin == fA after 12 steps); 400 float4 stores
    if (tid < TILE * (TILE / 4) / 1) {
        // loop kept general: 400 <= 512 so single pass with guard
    }
    {
        int i = tid;
        if (i < TILE * (TILE / 4)) {
            int r  = i / (TILE / 4);
            int c4 = (i - r * (TILE / 4)) * 4;
            const float* p = fin + (IH + r) * PITCH + IH + c4;
            float4 v = make_float4(p[0], p[1], p[2], p[3]);
            *(float4*)&db[(size_t)(oy + r) * WIMG + ox + c4] = v;
        }
    }
}

extern "C" void kernel_launch(void* const* d_in, const int* in_sizes, int n_in,
                              void* d_out, int out_size, void* d_ws, size_t ws_size,
                              hipStream_t stream)
{
    const float* aff  = (const float*)d_in[0];
    const float* feat = (const float*)d_in[1];
    float* out = (float*)d_out;

    char* ws = (char*)d_ws;
    float*   wsFrame = (float*)ws;
    __half2* wA      = (__half2*)(ws + WS_FRAME_B);
    float*   wC      = (float*)(ws + WS_FRAME_B + WS_WA_B);

    dim3 blk(NT, 1, 1);
    dim3 grd(WIMG / TILE, HIMG / TILE, BN);   // 16 x 12 x 8 = 1536 blocks

    if (ws_size >= WS_NEED) {
        precompute_w<<<dim3(BN * HW / 256), dim3(256), 0, stream>>>(aff, wA, wC);
        affprop12<true><<<grd, blk, 0, stream>>>(aff, wA, wC, feat, wsFrame);
        affprop12<true><<<grd, blk, 0, stream>>>(aff, wA, wC, wsFrame, out);
    } else {
        // fallback: normalize in-kernel (needs only one frame of scratch)
        affprop12<false><<<grd, blk, 0, stream>>>(aff, nullptr, nullptr, feat, wsFrame);
        affprop12<false><<<grd, blk, 0, stream>>>(aff, nullptr, nullptr, wsFrame, out);
    }
}

// Round 5
// 219.877 us; speedup vs baseline: 1.8263x; 1.2022x over previous
//
#include <hip/hip_runtime.h>
#include <hip/hip_fp16.h>
#include <cstddef>

// AffinityPropagate: per-pixel normalized 3x3 stencil, 24 steps.
// R5: T=12 x 2 launches, tile 40x40 (weight region 64x64). Thread = 1 col x 8
// rows (tid = g*64 + c; wave = 64 contiguous cols) -> ALL LDS traffic is
// lane-stride-1 b32 (2 lanes/bank = free, m136). R4's 2x4 units had 4-way
// write conflicts: SQ_LDS_BANK_CONFLICT 2.04e7 cyc/dispatch ~= 43% of time.
// Rolling 3x3 register window, 3 reads + 1 write per row-step.
// Launch 1 normalizes weights in-kernel (redundant region reads, L3-absorbed)
// and stores interior packed weights (half8 taps + f32 center) to d_ws;
// launch 2 loads them. 2 dispatches total (precompute folded in).
//
// Tap order: w0=NW w1=N w2=NE w3=W [center] w4=E w5=SW w6=S w7=SE
//
// Ring/frontier: staged halo 13 (66x66), weight halo 12 (64x64 = staged rows/
// cols 1..64, rewritten every step). Valid staged rings after step s: [s,65-s];
// after 12 steps rows/cols 12..53 valid; output tile is 13..52. Out-of-image
// px have all-zero weights -> stay exactly 0 = zero padding.

#define HIMG 480
#define WIMG 640
#define HW   (HIMG * WIMG)
#define BN   8

#define TILE   40
#define TSTEPS 12
#define IH     13                // staged halo
#define WHL    12                // weight halo
#define SW     66                // staged rows/cols
#define PITCH  68                // LDS row pitch (floats)
#define NT     512

#define WS_FRAME_B  ((size_t)BN * HW * 4)            // 9,830,400
#define WS_WA_B     ((size_t)BN * HW * 16)           // 39,321,600
#define WS_WC_B     ((size_t)BN * HW * 4)            // 9,830,400
#define WS_NEED     (WS_FRAME_B + WS_WA_B + WS_WC_B) // 58,982,400

// MODE: 0 = normalize in-kernel + store interior weights to wA/wC
//       1 = load packed weights from wA/wC
//       2 = normalize in-kernel, no store (fallback when ws too small)
template <int MODE>
__global__ __launch_bounds__(NT, 4) void affprop12(
    const float* __restrict__ aff,
    __half2* __restrict__ wA,
    float* __restrict__ wC,
    const float* __restrict__ src,
    float* __restrict__ dst)
{
    __shared__ float fA[SW * PITCH];
    __shared__ float fB[SW * PITCH];

    const int tid = threadIdx.x;
    const int ox  = blockIdx.x * TILE;
    const int oy  = blockIdx.y * TILE;
    const int b   = blockIdx.z;

    const float* __restrict__ sb = src + (size_t)b * HW;
    float*       __restrict__ db = dst + (size_t)b * HW;

    // ---- stage input region [oy-13, oy+53) x [ox-13, ox+53), 0 outside image
    for (int i = tid; i < SW * SW; i += NT) {
        int r  = i / SW;
        int c  = i - r * SW;
        int gy = oy - IH + r;
        int gx = ox - IH + c;
        float v = 0.f;
        if ((unsigned)gy < (unsigned)HIMG && (unsigned)gx < (unsigned)WIMG)
            v = sb[gy * WIMG + gx];
        fA[r * PITCH + c] = v;
    }
    // ---- zero-fill buffer B (deterministic stale rings)
    for (int i = tid; i < SW * PITCH / 4; i += NT)
        *(float4*)&fB[4 * i] = make_float4(0.f, 0.f, 0.f, 0.f);

    // ---- per-thread: weight column c, row group g (8 rows)
    const int c  = tid & 63;          // weight col 0..63
    const int g  = tid >> 6;          // row group 0..7
    const int sc = c + 1;             // staged col of this thread's outputs

    __half2 wv[8][4];   // [row i][tap pair (01)(23)(45)(67)]
    float   wcc[8];     // center weights (f32)

    #pragma unroll
    for (int i = 0; i < 8; ++i) {
        const int gy = oy - WHL + 8 * g + i;
        const int gx = ox - WHL + c;
        const bool in = (unsigned)gy < (unsigned)HIMG && (unsigned)gx < (unsigned)WIMG;
        const size_t idx = (size_t)b * HW + (size_t)gy * WIMG + gx;

        if (MODE == 1) {
            if (in) {
                union { float4 f4; __half2 h[4]; } u;
                u.f4 = *(const float4*)(wA + 4 * idx);
                wv[i][0] = u.h[0]; wv[i][1] = u.h[1];
                wv[i][2] = u.h[2]; wv[i][3] = u.h[3];
                wcc[i] = wC[idx];
            } else {
                __half2 z = __floats2half2_rn(0.f, 0.f);
                wv[i][0] = z; wv[i][1] = z; wv[i][2] = z; wv[i][3] = z;
                wcc[i] = 0.f;
            }
        } else {
            float w[8];
            float s = 0.f;
            if (in) {
                const float* ap = aff + (size_t)b * 8 * HW + (size_t)gy * WIMG + gx;
                #pragma unroll
                for (int k = 0; k < 8; ++k) { w[k] = ap[(size_t)k * HW]; s += fabsf(w[k]); }
            } else {
                #pragma unroll
                for (int k = 0; k < 8; ++k) w[k] = 0.f;
                s = 1.f;
            }
            float rr  = in ? 1.0f / s : 0.f;
            float acc = 0.f;
            #pragma unroll
            for (int k = 0; k < 8; ++k) { w[k] *= rr; acc += w[k]; }

            union { float4 f4; __half2 h[4]; } u;
            u.h[0] = __floats2half2_rn(w[0], w[1]);
            u.h[1] = __floats2half2_rn(w[2], w[3]);
            u.h[2] = __floats2half2_rn(w[4], w[5]);
            u.h[3] = __floats2half2_rn(w[6], w[7]);
            wv[i][0] = u.h[0]; wv[i][1] = u.h[1];
            wv[i][2] = u.h[2]; wv[i][3] = u.h[3];
            wcc[i] = in ? 1.0f - acc : 0.f;

            if (MODE == 0) {
                // store interior weights for launch 2 (each image px interior
                // to exactly one block)
                if ((unsigned)(gy - oy) < (unsigned)TILE &&
                    (unsigned)(gx - ox) < (unsigned)TILE) {
                    *(float4*)(wA + 4 * idx) = u.f4;
                    wC[idx] = wcc[i];
                }
            }
        }
    }
    __syncthreads();

    // ---- 12 fused steps; rolling 3x3 window, stride-1 LDS only
    const float* fin = fA;
    float*       fo  = fB;

    #pragma unroll 1
    for (int s = 0; s < TSTEPS; ++s) {
        const float* rp = fin + (8 * g) * PITCH + c;   // staged cols sc-1..sc+1
        float a0 = rp[0], a1 = rp[1], a2 = rp[2];
        rp += PITCH;
        float b0 = rp[0], b1 = rp[1], b2 = rp[2];
        float* wp = fo + (8 * g + 1) * PITCH + sc;

        #pragma unroll
        for (int i = 0; i < 8; ++i) {
            rp += PITCH;
            float c0 = rp[0], c1 = rp[1], c2 = rp[2];

            float o = wcc[i] * b1
                + __low2float (wv[i][0]) * a0    // NW
                + __high2float(wv[i][0]) * a1    // N
                + __low2float (wv[i][1]) * a2    // NE
                + __high2float(wv[i][1]) * b0    // W
                + __low2float (wv[i][2]) * b2    // E
                + __high2float(wv[i][2]) * c0    // SW
                + __low2float (wv[i][3]) * c1    // S
                + __high2float(wv[i][3]) * c2;   // SE

            *wp = o;
            wp += PITCH;
            a0 = b0; a1 = b1; a2 = b2;
            b0 = c0; b1 = c1; b2 = c2;
        }
        __syncthreads();
        const float* t = fin; fin = fo; fo = (float*)t;
    }

    // ---- store 40x40 tile (fin == fA after 12 steps)
    for (int i = tid; i < TILE * (TILE / 4); i += NT) {
        int r  = i / (TILE / 4);
        int c4 = (i - r * (TILE / 4)) * 4;
        const float* p = fin + (IH + r) * PITCH + IH + c4;
        float4 v = make_float4(p[0], p[1], p[2], p[3]);
        *(float4*)&db[(size_t)(oy + r) * WIMG + ox + c4] = v;
    }
}

extern "C" void kernel_launch(void* const* d_in, const int* in_sizes, int n_in,
                              void* d_out, int out_size, void* d_ws, size_t ws_size,
                              hipStream_t stream)
{
    const float* aff  = (const float*)d_in[0];
    const float* feat = (const float*)d_in[1];
    float* out = (float*)d_out;

    char* ws = (char*)d_ws;
    float*   wsFrame = (float*)ws;
    __half2* wA      = (__half2*)(ws + WS_FRAME_B);
    float*   wC      = (float*)(ws + WS_FRAME_B + WS_WA_B);

    dim3 blk(NT, 1, 1);
    dim3 grd(WIMG / TILE, HIMG / TILE, BN);   // 16 x 12 x 8 = 1536 blocks

    if (ws_size >= WS_NEED) {
        affprop12<0><<<grd, blk, 0, stream>>>(aff, wA, wC, feat, wsFrame);
        affprop12<1><<<grd, blk, 0, stream>>>(aff, wA, wC, wsFrame, out);
    } else {
        affprop12<2><<<grd, blk, 0, stream>>>(aff, nullptr, nullptr, feat, wsFrame);
        affprop12<2><<<grd, blk, 0, stream>>>(aff, nullptr, nullptr, wsFrame, out);
    }
}